// Round 3
// baseline (193.418 us; speedup 1.0000x reference)
//
#include <hip/hip_runtime.h>

// Sparse 3D conv (K=3, stride=2, pad=1) via GATHER into dense output.
// Inputs: features [N,32] f32, W [3,3,3,32,64] f32, coors [N,4] i32 (b,z,y,x).
// Output: [B,64,64,64,64] f32, flat. No global atomics, no output memset.

#define CIN   32
#define COUT  64
#define OUTD  64
#define IND   128
#define TILE  4
#define RGN   (2*TILE+1)   // 9: input region edge per tile
#define CAP   1024         // pair-list capacity (mean ~41/tile)
#define NPTS  128

// ---------- map build: voxel -> head of point-index chain ----------
__global__ void build_map(const int* __restrict__ coors, int* __restrict__ map,
                          int* __restrict__ nxt, int N)
{
    int i = blockIdx.x * blockDim.x + threadIdx.x;
    if (i >= N) return;
    const int b = coors[i*4], z = coors[i*4+1], y = coors[i*4+2], x = coors[i*4+3];
    const int v = ((b*IND + z)*IND + y)*IND + x;
    nxt[i] = atomicExch(&map[v], i);   // linked list handles duplicate coords
}

// ---------- gather: one block per 4x4x4 output tile ----------
__global__ __launch_bounds__(256) void gather_tile(
    const float* __restrict__ feats, const float* __restrict__ Wt,
    const int* __restrict__ map, const int* __restrict__ nxt,
    float* __restrict__ out)
{
    __shared__ float acc[TILE*TILE*TILE*COUT];   // 16 KB
    __shared__ int   list[CAP];                  // 4 KB
    __shared__ int   cnt;

    const int tid = threadIdx.x;
    int t = blockIdx.x;
    const int ox0 = (t & 15) * TILE; t >>= 4;
    const int oy0 = (t & 15) * TILE; t >>= 4;
    const int oz0 = (t & 15) * TILE; t >>= 4;
    const int b   = t;

    for (int i = tid; i < TILE*TILE*TILE*COUT; i += 256) acc[i] = 0.f;
    if (tid == 0) cnt = 0;
    __syncthreads();

    // Phase 1: scan 9^3 input region; each occupied voxel feeds <=8 tile outputs.
    const int mapBase = b * IND * IND * IND;
    for (int idx = tid; idx < RGN*RGN*RGN; idx += 256) {
        const int rx = idx % RGN, ry = (idx / RGN) % RGN, rz = idx / (RGN*RGN);
        const int px = 2*ox0 - 1 + rx;
        const int py = 2*oy0 - 1 + ry;
        const int pz = 2*oz0 - 1 + rz;
        if ((unsigned)px >= IND || (unsigned)py >= IND || (unsigned)pz >= IND) continue;
        int j = map[mapBase + (pz*IND + py)*IND + px];
        if (j < 0) continue;

        // per-axis: k = p+1-2o must be in {0,1,2}; parity fixes k mod 2
        const int kpx = (px+1)&1, ox1 = (px+1-kpx)>>1;
        const int kpy = (py+1)&1, oy1 = (py+1-kpy)>>1;
        const int kpz = (pz+1)&1, oz1 = (pz+1-kpz)>>1;

        bool ok[8]; int pre[8];
        #pragma unroll
        for (int cz = 0; cz < 2; ++cz)
        #pragma unroll
        for (int cy = 0; cy < 2; ++cy)
        #pragma unroll
        for (int cx = 0; cx < 2; ++cx) {
            const int kz = kpz + 2*cz, ky = kpy + 2*cy, kx = kpx + 2*cx;
            const int olz = oz1 - cz - oz0, oly = oy1 - cy - oy0, olx = ox1 - cx - ox0;
            const int ci = (cz*2 + cy)*2 + cx;
            ok[ci]  = (kz <= 2) && (ky <= 2) && (kx <= 2) &&
                      ((unsigned)olz < TILE) && ((unsigned)oly < TILE) &&
                      ((unsigned)olx < TILE);
            pre[ci] = (((kz*3 + ky)*3 + kx) << 6) | ((olz*TILE + oly)*TILE + olx);
        }
        for (; j >= 0; j = nxt[j]) {        // walk duplicate-coordinate chain
            #pragma unroll
            for (int ci = 0; ci < 8; ++ci) {
                if (ok[ci]) {
                    const int s = atomicAdd(&cnt, 1);
                    if (s < CAP) list[s] = (j << 11) | pre[ci];
                }
            }
        }
    }
    __syncthreads();

    // Phase 2: one wave per pair (64 lanes = 64 output channels), ds_add accumulate.
    const int n = min(cnt, CAP);
    const int wv = tid >> 6, ch = tid & 63;
    for (int i = wv; i < n; i += 4) {
        const int e = list[i];
        const int vox = e & 63, k = (e >> 6) & 31, j = e >> 11;
        const float* fp = feats + (size_t)j * CIN;       // broadcast reads
        const float* wp = Wt + k * (CIN*COUT) + ch;      // coalesced reads
        float s = 0.f;
        #pragma unroll
        for (int c = 0; c < CIN; ++c) s += fp[c] * wp[c * COUT];
        atomicAdd(&acc[vox * COUT + ch], s);             // ds_add_f32, conflict-free
    }
    __syncthreads();

    // Phase 3: stream tile to global. Contiguous run per (vz,vy) row is
    // TILE*COUT = 256 floats (4 x-positions x 64 ch). 16 rows of 256.
    #pragma unroll
    for (int it = 0; it < 4; ++it) {
        const int i = (it*256 + tid) * 4;      // float index in tile [0,4096)
        const int row = i >> 8;                // (vz,vy) row: 16 rows of 256 floats
        const int vz = row >> 2, vy = row & 3;
        const int inrow = i & 255;
        const size_t g = ((((size_t)b*OUTD + (oz0+vz))*OUTD + (oy0+vy))*OUTD + ox0)*COUT + inrow;
        *(float4*)(out + g) = *(const float4*)(acc + i);
    }
}

// ---------- fallback (ws too small): round-1 scatter ----------
__global__ __launch_bounds__(256, 4) void spconv_scatter(
    const float* __restrict__ feats, const float* __restrict__ Wt,
    const int* __restrict__ coors, float* __restrict__ out, int N)
{
    __shared__ float sf[NPTS][CIN];
    __shared__ int   sc[NPTS][4];
    __shared__ int   vf[NPTS];

    const int tid = threadIdx.x;
    const int ch  = tid & 63;
    const int wv  = tid >> 6;
    const int base = blockIdx.x * NPTS;
    const int npts = min(NPTS, (int)(N - base));
    if (npts <= 0) return;

    for (int i = tid; i < npts * CIN; i += 256) sf[0][i] = feats[base * CIN + i];
    for (int i = tid; i < npts * 4; i += 256) ((int*)sc)[i] = coors[base * 4 + i];
    __syncthreads();

    for (int off = 0; off < 27; ++off) {
        const int kz = off / 9, ky = (off / 3) % 3, kx = off % 3;
        if (tid < npts) {
            const int p  = tid;
            const int nz = sc[p][1] + 1 - kz;
            const int ny = sc[p][2] + 1 - ky;
            const int nx = sc[p][3] + 1 - kx;
            const int m  = nz | ny | nx;
            const int oz = nz >> 1, oy = ny >> 1, ox = nx >> 1;
            const bool v = ((m & 0x80000001) == 0) &&
                           (oz < OUTD) && (oy < OUTD) && (ox < OUTD);
            vf[p] = v ? (((sc[p][0] * OUTD + oz) * OUTD + oy) * OUTD + ox) : -1;
        }
        const float* wp = Wt + off * (CIN * COUT) + ch;
        float w[CIN];
        #pragma unroll
        for (int c = 0; c < CIN; ++c) w[c] = wp[c * COUT];
        __syncthreads();
        for (int p = wv; p < npts; p += 4) {
            const int f = vf[p];
            if (f >= 0) {
                float s = 0.f;
                #pragma unroll
                for (int c = 0; c < CIN; ++c) s += sf[p][c] * w[c];
                atomicAdd(&out[(size_t)f * COUT + ch], s);
            }
        }
        __syncthreads();
    }
}

extern "C" void kernel_launch(void* const* d_in, const int* in_sizes, int n_in,
                              void* d_out, int out_size, void* d_ws, size_t ws_size,
                              hipStream_t stream) {
    const float* feats = (const float*)d_in[0];
    const float* Wt    = (const float*)d_in[1];
    const int*   coors = (const int*)d_in[2];
    float*       out   = (float*)d_out;

    const int N = in_sizes[0] / CIN;
    const int B = out_size / (OUTD * OUTD * OUTD * COUT);

    const size_t mapElems = (size_t)B * IND * IND * IND;
    const size_t need = (mapElems + (size_t)N) * sizeof(int);

    if (ws_size >= need) {
        int* map = (int*)d_ws;
        int* nxt = map + mapElems;
        hipMemsetAsync(map, 0xFF, mapElems * sizeof(int), stream);   // all -1
        build_map<<<(N + 255) / 256, 256, 0, stream>>>(coors, map, nxt, N);
        const int tiles = B * (OUTD/TILE) * (OUTD/TILE) * (OUTD/TILE);
        gather_tile<<<tiles, 256, 0, stream>>>(feats, Wt, map, nxt, out);
    } else {
        hipMemsetAsync(d_out, 0, (size_t)out_size * sizeof(float), stream);
        spconv_scatter<<<(N + NPTS - 1) / NPTS, 256, 0, stream>>>(feats, Wt, coors, out, N);
    }
}